// Round 12
// baseline (259.377 us; speedup 1.0000x reference)
//
#include <hip/hip_runtime.h>
#include <hip/hip_bf16.h>
#include <math.h>

#define H 512
#define S 65
#define SP 80                // padded s-dimension (rows 65..79 zero/garbage)
#define HS (H * S)           // 33280
#define PHS (H * SP)         // 40960
#define KS3 24
#define KS4 16

// Layouts:
//  yT:    [SP][H]; pad rows zeroed by embed; combine writes rows <65 only.
//  kqvp:  layer1 (KSPLIT=1): 9 arrays (slot*3+which)*PHS.
//         layers2/3 (KSPLIT=2): 6 arrays ((slot*3+which)*2+kidx)*PHS.
//  att1:  3 heads x PHS; att2: PHS (pad rows poison, never read as output).
//  plin1: 6 partials x PHS; plin2: 4 partials x PHS.

// ---------------------------------------------------------------------------
__global__ void scale_embed_kernel(const float* __restrict__ inp,
                                   const float* __restrict__ emb,
                                   float* __restrict__ yT) {
    int i = blockIdx.x * blockDim.x + threadIdx.x;
    if (i < PHS) {
        int s = i / H;
        int h = i % H;
        float v = 0.f;
        if (s < S) {
            float x = (s == 64) ? 1.0f : inp[s];
            v = emb[h * S + s] * x;
        }
        yT[i] = v;
    }
}

// ---------------------------------------------------------------------------
__device__ __forceinline__ void mac4(float4& c, float ax, float ay, float az,
                                     float aw, const float4& w0, const float4& w1,
                                     const float4& w2, const float4& w3) {
    c.x = fmaf(ax, w0.x, c.x); c.y = fmaf(ax, w0.y, c.y);
    c.z = fmaf(ax, w0.z, c.z); c.w = fmaf(ax, w0.w, c.w);
    c.x = fmaf(ay, w1.x, c.x); c.y = fmaf(ay, w1.y, c.y);
    c.z = fmaf(ay, w1.z, c.z); c.w = fmaf(ay, w1.w, c.w);
    c.x = fmaf(az, w2.x, c.x); c.y = fmaf(az, w2.y, c.y);
    c.z = fmaf(az, w2.z, c.z); c.w = fmaf(az, w2.w, c.w);
    c.x = fmaf(aw, w3.x, c.x); c.y = fmaf(aw, w3.y, c.y);
    c.z = fmaf(aw, w3.z, c.z); c.w = fmaf(aw, w3.w, c.w);
}

// ---------------------------------------------------------------------------
// KQV GEMM, 32-wide n-tiles.  C[s][n] = sum_k yT[s][k] * W[n][k].
// KSPLIT=1: grid.x=16 (144 blocks layer1, single dispatch pass), K=512/block.
// KSPLIT=2: grid.x=32 (96 blocks layers 2/3), K=256/block.
// ---------------------------------------------------------------------------
template <int KSPLIT>
__global__ void __launch_bounds__(256, 1)
kqv_gemm_tiled(const float* __restrict__ wq,
               const float* __restrict__ wk,
               const float* __restrict__ wv,
               int mat0,
               const float* __restrict__ yT,
               float* __restrict__ part) {
    int slot  = blockIdx.z;
    int which = blockIdx.y;
    int mat = mat0 + slot;
    const float* W = (which == 0 ? wk : (which == 1 ? wq : wv)) + (size_t)mat * H * H;

    int n0   = (blockIdx.x & 15) * 32;
    int kidx = blockIdx.x >> 4;       // 0 when KSPLIT=1
    const int NCH = 8 / KSPLIT;

    __shared__ float Wt[64 * 32];     // [k][n swizzled]
    __shared__ float As[SP * 68];     // stride 68 = conflict-free

    int t  = threadIdx.x;
    int nq = t & 7;                   // n = n0 + 4*nq
    int g  = t >> 3;                  // 0..31; s = g, g+32, (g+64 if g<16)
    bool r2 = (g < 16);

    float4 acc0 = {0,0,0,0}, acc1 = {0,0,0,0}, acc2 = {0,0,0,0};

    for (int ch = 0; ch < NCH; ++ch) {
        int kc0 = (kidx * NCH + ch) * 64;
#pragma unroll
        for (int c = 0; c < 2; ++c) {
            int f = c * 256 + t;
            int wn  = f >> 4;         // 0..31
            int kf4 = f & 15;
            float4 w4 = *(const float4*)(W + (size_t)(n0 + wn) * H + kc0 + 4 * kf4);
            int sw = ((wn >> 2) ^ (kf4 & 7));
            int base = (4 * kf4) * 32 + 4 * sw + (wn & 3);
            Wt[base     ] = w4.x;
            Wt[base + 32] = w4.y;
            Wt[base + 64] = w4.z;
            Wt[base + 96] = w4.w;
        }
#pragma unroll
        for (int c = 0; c < 5; ++c) {
            int f = c * 256 + t;
            int as  = f >> 4;
            int kf4 = f & 15;
            *(float4*)(&As[as * 68 + 4 * kf4]) =
                *(const float4*)(yT + (size_t)as * H + kc0 + 4 * kf4);
        }
        __syncthreads();

#pragma unroll
        for (int k4 = 0; k4 < 16; ++k4) {
            int swc = 4 * (nq ^ (k4 & 7));
            float4 w0 = *(const float4*)(&Wt[(4 * k4 + 0) * 32 + swc]);
            float4 w1 = *(const float4*)(&Wt[(4 * k4 + 1) * 32 + swc]);
            float4 w2 = *(const float4*)(&Wt[(4 * k4 + 2) * 32 + swc]);
            float4 w3 = *(const float4*)(&Wt[(4 * k4 + 3) * 32 + swc]);
            {
                float4 a = *(const float4*)(&As[g * 68 + 4 * k4]);
                mac4(acc0, a.x, a.y, a.z, a.w, w0, w1, w2, w3);
            }
            {
                float4 a = *(const float4*)(&As[(g + 32) * 68 + 4 * k4]);
                mac4(acc1, a.x, a.y, a.z, a.w, w0, w1, w2, w3);
            }
            if (r2) {
                float4 a = *(const float4*)(&As[(g + 64) * 68 + 4 * k4]);
                mac4(acc2, a.x, a.y, a.z, a.w, w0, w1, w2, w3);
            }
        }
        __syncthreads();
    }

    float* P = part + (size_t)((slot * 3 + which) * KSPLIT + kidx) * PHS;
    *(float4*)(P + (size_t)g * H + n0 + 4 * nq) = acc0;
    *(float4*)(P + (size_t)(g + 32) * H + n0 + 4 * nq) = acc1;
    if (r2) *(float4*)(P + (size_t)(g + 64) * H + n0 + 4 * nq) = acc2;
}

// ---------------------------------------------------------------------------
// Score quarter t of dot(ka, q_b); NS = number of K-split partials of q.
// ---------------------------------------------------------------------------
template <int NS>
__device__ __forceinline__ float score_part(const float* __restrict__ Q,
                                            const float* __restrict__ ka,
                                            int b, int t) {
    const float4* q0 = (const float4*)(Q + (size_t)b * H) + t * 32;
    const float4* q1 = (const float4*)(Q + PHS + (size_t)b * H) + t * 32;
    const float4* kl = (const float4*)ka + t * 32;
    float4 c0 = {0,0,0,0}, c1 = {0,0,0,0};
#pragma unroll
    for (int u = 0; u < 32; u += 2) {
        float4 qa = q0[u], qc = q0[u + 1];
        float4 k0 = kl[u], k1 = kl[u + 1];
        if (NS == 2) {
            float4 qb = q1[u], qd = q1[u + 1];
            qa.x += qb.x; qa.y += qb.y; qa.z += qb.z; qa.w += qb.w;
            qc.x += qd.x; qc.y += qd.y; qc.z += qd.z; qc.w += qd.w;
        }
        c0.x = fmaf(k0.x, qa.x, c0.x);
        c0.y = fmaf(k0.y, qa.y, c0.y);
        c0.z = fmaf(k0.z, qa.z, c0.z);
        c0.w = fmaf(k0.w, qa.w, c0.w);
        c1.x = fmaf(k1.x, qc.x, c1.x);
        c1.y = fmaf(k1.y, qc.y, c1.y);
        c1.z = fmaf(k1.z, qc.z, c1.z);
        c1.w = fmaf(k1.w, qc.w, c1.w);
    }
    return ((c0.x + c0.y) + (c0.z + c0.w)) + ((c1.x + c1.y) + (c1.z + c1.w));
}

// ---------------------------------------------------------------------------
// Attention row a, head slot. NS = K-split count of kqvp arrays.
// ---------------------------------------------------------------------------
template <int NS>
__global__ void attn_kernel(const float* __restrict__ kqvp,
                            float* __restrict__ att) {
    int a = blockIdx.x;
    int slot = blockIdx.y;
    int tid = threadIdx.x;   // 256

    const float* base = kqvp + (size_t)slot * 3 * NS * PHS;
    const float* K0 = base;
    const float* Q0 = base + (size_t)NS * PHS;
    const float* V0 = base + (size_t)2 * NS * PHS;
    const float* K1 = K0 + PHS;   // used only when NS==2
    const float* V1 = V0 + PHS;
    float* ao = att + (size_t)slot * PHS + (size_t)a * H;

    __shared__ float ka[H];
    __shared__ float sp[4 * 65];
    __shared__ float smv[S];
    __shared__ float p[S];

    if (NS == 2) {
        ka[tid]       = K0[(size_t)a * H + tid]       + K1[(size_t)a * H + tid];
        ka[tid + 256] = K0[(size_t)a * H + tid + 256] + K1[(size_t)a * H + tid + 256];
    } else {
        ka[tid]       = K0[(size_t)a * H + tid];
        ka[tid + 256] = K0[(size_t)a * H + tid + 256];
    }
    __syncthreads();

    {
        int b = tid & 63;
        int t = tid >> 6;          // wave-uniform
        sp[t * 65 + b] = score_part<NS>(Q0, ka, b, t);
        if (tid < 4) sp[tid * 65 + 64] = score_part<NS>(Q0, ka, 64, tid);
    }
    __syncthreads();

    if (tid < S) {
        smv[tid] = (sp[tid] + sp[65 + tid]) + (sp[130 + tid] + sp[195 + tid]);
    }
    __syncthreads();

    float maxv = -INFINITY;
    for (int i = 0; i < S; ++i) maxv = fmaxf(maxv, smv[i]);
    float sum = 0.0f;
    for (int i = 0; i < S; ++i) sum += expf(smv[i] - maxv);
    float inv = 1.0f / sum;
    if (tid < S) p[tid] = expf(smv[tid] - maxv) * inv;
    __syncthreads();

#pragma unroll
    for (int rep = 0; rep < 2; ++rep) {
        int hh = tid + rep * 256;
        float a0 = 0.f, a1 = 0.f;
#pragma unroll 4
        for (int b = 0; b < 64; b += 2) {
            float v0 = V0[(size_t)(b    ) * H + hh];
            float v1 = V0[(size_t)(b + 1) * H + hh];
            if (NS == 2) {
                v0 += V1[(size_t)(b    ) * H + hh];
                v1 += V1[(size_t)(b + 1) * H + hh];
            }
            a0 = fmaf(p[b    ], v0, a0);
            a1 = fmaf(p[b + 1], v1, a1);
        }
        {
            float v0 = V0[(size_t)64 * H + hh];
            if (NS == 2) v0 += V1[(size_t)64 * H + hh];
            a0 = fmaf(p[64], v0, a0);
        }
        ao[hh] = a0 + a1;
    }
}

// ---------------------------------------------------------------------------
// 4-row linear block (round-11 proven).
// ---------------------------------------------------------------------------
__device__ __forceinline__ void lin4row_dev(const float* __restrict__ att,
                                            int col0,
                                            const float* __restrict__ L,
                                            float* __restrict__ dst,
                                            int s0, int tid) {
    __shared__ float Ar[4 * 256];
    __shared__ float4 red[4 * 128];

    {
        int rr = tid >> 6;
        int cc = tid & 63;
        *(float4*)(&Ar[rr * 256 + cc * 4]) =
            *(const float4*)(att + (size_t)(s0 + rr) * H + col0 + cc * 4);
    }
    __syncthreads();

    int h4 = (tid & 127) * 4;
    int jh = tid >> 7;
    const float* Lj = L + (size_t)(jh * 128) * H + h4;
    const float* A0 = Ar + jh * 128;

    float4 c0 = {0,0,0,0}, c1 = {0,0,0,0}, c2 = {0,0,0,0}, c3 = {0,0,0,0};
#pragma unroll 8
    for (int j = 0; j < 128; ++j) {
        float4 L4 = *(const float4*)(Lj + (size_t)j * H);
        float a0 = A0[j], a1 = A0[256 + j], a2 = A0[512 + j], a3 = A0[768 + j];
        c0.x = fmaf(a0, L4.x, c0.x); c0.y = fmaf(a0, L4.y, c0.y);
        c0.z = fmaf(a0, L4.z, c0.z); c0.w = fmaf(a0, L4.w, c0.w);
        c1.x = fmaf(a1, L4.x, c1.x); c1.y = fmaf(a1, L4.y, c1.y);
        c1.z = fmaf(a1, L4.z, c1.z); c1.w = fmaf(a1, L4.w, c1.w);
        c2.x = fmaf(a2, L4.x, c2.x); c2.y = fmaf(a2, L4.y, c2.y);
        c2.z = fmaf(a2, L4.z, c2.z); c2.w = fmaf(a2, L4.w, c2.w);
        c3.x = fmaf(a3, L4.x, c3.x); c3.y = fmaf(a3, L4.y, c3.y);
        c3.z = fmaf(a3, L4.z, c3.z); c3.w = fmaf(a3, L4.w, c3.w);
    }

    if (jh == 1) {
        int x = tid & 127;
        red[x] = c0; red[128 + x] = c1; red[256 + x] = c2; red[384 + x] = c3;
    }
    __syncthreads();
    if (jh == 0) {
        float4 r0 = red[tid], r1 = red[128 + tid], r2 = red[256 + tid], r3 = red[384 + tid];
        c0.x += r0.x; c0.y += r0.y; c0.z += r0.z; c0.w += r0.w;
        c1.x += r1.x; c1.y += r1.y; c1.z += r1.z; c1.w += r1.w;
        c2.x += r2.x; c2.y += r2.y; c2.z += r2.z; c2.w += r2.w;
        c3.x += r3.x; c3.y += r3.y; c3.z += r3.z; c3.w += r3.w;
        *(float4*)(dst + (size_t)(s0 + 0) * H + h4) = c0;
        *(float4*)(dst + (size_t)(s0 + 1) * H + h4) = c1;
        *(float4*)(dst + (size_t)(s0 + 2) * H + h4) = c2;
        *(float4*)(dst + (size_t)(s0 + 3) * H + h4) = c3;
    }
}

// ---------------------------------------------------------------------------
// Mega linear: lin1 (6 segs) + lin2 segs 0..3 + lin3 row-64 slices 0..15.
// ---------------------------------------------------------------------------
__global__ void mega_lin_kernel(const float* __restrict__ att1,
                                const float* __restrict__ lin1,
                                const float* __restrict__ lin2,
                                const float* __restrict__ lin3,
                                float* __restrict__ plin1,
                                float* __restrict__ plin2,
                                float* __restrict__ tpart) {
    int bx = blockIdx.x;
    int tid = threadIdx.x;

    if (bx < 170) {
        int seg = bx / 17;      // 0..9
        int p   = bx % 17;
        const float* att;
        const float* L;
        float* dst;
        if (seg < 6) {
            att = att1 + (size_t)(seg >> 1) * PHS;
            L   = lin1 + (size_t)(seg * 256) * H;
            dst = plin1 + (size_t)seg * PHS;
        } else {
            int s2 = seg - 6;
            att = att1 + (size_t)(s2 >> 1) * PHS;
            L   = lin2 + (size_t)(s2 * 256) * H;
            dst = plin2 + (size_t)s2 * PHS;
        }
        lin4row_dev(att, (seg & 1) * 256, L, dst, p * 4, tid);
    } else {
        int idx = bx - 170;                   // 0..63
        int j2 = (idx & 3) * 256 + tid;
        int ks = idx >> 2;                    // 0..15
        const float* row = att1 + (size_t)(ks >> 3) * PHS + (size_t)64 * H;
        int j0 = (ks & 7) * 64;
        int jbase = ks * 64;
        float a0 = 0.f, a1 = 0.f, a2 = 0.f, a3 = 0.f;
        for (int j = 0; j < 64; j += 4) {
            a0 = fmaf(row[j0 + j + 0], lin3[(size_t)(jbase + j + 0) * 1024 + j2], a0);
            a1 = fmaf(row[j0 + j + 1], lin3[(size_t)(jbase + j + 1) * 1024 + j2], a1);
            a2 = fmaf(row[j0 + j + 2], lin3[(size_t)(jbase + j + 2) * 1024 + j2], a2);
            a3 = fmaf(row[j0 + j + 3], lin3[(size_t)(jbase + j + 3) * 1024 + j2], a3);
        }
        tpart[ks * 1024 + j2] = (a0 + a1) + (a2 + a3);
    }
}

// 6-way partial sum + relu -> yT rows <65
__global__ void combine6_relu_kernel(const float* __restrict__ part,
                                     float* __restrict__ yT) {
    int i = blockIdx.x * 256 + threadIdx.x;   // 130*256 == HS
    float s = 0.f;
#pragma unroll
    for (int p = 0; p < 6; ++p) s += part[(size_t)p * PHS + i];
    yT[i] = fmaxf(s, 0.0f);
}

// ---------------------------------------------------------------------------
// Fused: lin2 segs 4,5 (from att2) + sum plin2[0..3] + relu -> yT. 130 blocks.
// Round-6 stage-7 pattern: per-wave s is uniform (broadcast A reads),
// lin2 column reads wave-coalesced.
// ---------------------------------------------------------------------------
__global__ void lin2c_combine_kernel(const float* __restrict__ att2,
                                     const float* __restrict__ lin2,
                                     const float* __restrict__ plin2,
                                     float* __restrict__ yT) {
    int i = blockIdx.x * 256 + threadIdx.x;
    int s = i / H;
    int h = i % H;
    const float* row = att2 + (size_t)s * H;
    const float* L4 = lin2 + (size_t)1024 * H + h;
    const float* L5 = lin2 + (size_t)1280 * H + h;

    float a0 = 0.f, a1 = 0.f, a2 = 0.f, a3 = 0.f;
    for (int j = 0; j < 256; j += 4) {
        a0 = fmaf(row[j + 0], L4[(size_t)(j + 0) * H], a0);
        a1 = fmaf(row[j + 1], L4[(size_t)(j + 1) * H], a1);
        a2 = fmaf(row[j + 2], L4[(size_t)(j + 2) * H], a2);
        a3 = fmaf(row[j + 3], L4[(size_t)(j + 3) * H], a3);
    }
    for (int j = 0; j < 256; j += 4) {
        a0 = fmaf(row[256 + j + 0], L5[(size_t)(j + 0) * H], a0);
        a1 = fmaf(row[256 + j + 1], L5[(size_t)(j + 1) * H], a1);
        a2 = fmaf(row[256 + j + 2], L5[(size_t)(j + 2) * H], a2);
        a3 = fmaf(row[256 + j + 3], L5[(size_t)(j + 3) * H], a3);
    }
    float tot = (a0 + a1) + (a2 + a3)
              + plin2[i] + plin2[PHS + i] + plin2[2 * PHS + i] + plin2[3 * PHS + i];
    yT[i] = fmaxf(tot, 0.0f);
}

// ---------------------------------------------------------------------------
// Layer-3 attention (row 64 only) + lin3 slices 16..23. grid (4,8).
// kqvp layout here: 6 arrays (KSPLIT=2, slot=0).
// ---------------------------------------------------------------------------
__global__ void attn3_lin3c_kernel(const float* __restrict__ kqvp,
                                   const float* __restrict__ lin3,
                                   float* __restrict__ tpart) {
    int tid = threadIdx.x;
    int ks  = 16 + blockIdx.y;
    int j2  = blockIdx.x * 256 + tid;
    int j0  = (ks & 7) * 64;

    const float* K0 = kqvp;
    const float* K1 = kqvp + PHS;
    const float* Q0 = kqvp + 2 * (size_t)PHS;
    const float* V0 = kqvp + 4 * (size_t)PHS;
    const float* V1 = kqvp + 5 * (size_t)PHS;

    __shared__ float ka[H];
    __shared__ float sp[4 * 65];
    __shared__ float smv[S];
    __shared__ float p[S];
    __shared__ float att_s[64];

    ka[tid]       = K0[(size_t)64 * H + tid]       + K1[(size_t)64 * H + tid];
    ka[tid + 256] = K0[(size_t)64 * H + tid + 256] + K1[(size_t)64 * H + tid + 256];
    __syncthreads();

    {
        int b = tid & 63;
        int t = tid >> 6;
        sp[t * 65 + b] = score_part<2>(Q0, ka, b, t);
        if (tid < 4) sp[tid * 65 + 64] = score_part<2>(Q0, ka, 64, tid);
    }
    __syncthreads();

    if (tid < S) {
        smv[tid] = (sp[tid] + sp[65 + tid]) + (sp[130 + tid] + sp[195 + tid]);
    }
    __syncthreads();

    float maxv = -INFINITY;
    for (int i = 0; i < S; ++i) maxv = fmaxf(maxv, smv[i]);
    float sum = 0.0f;
    for (int i = 0; i < S; ++i) sum += expf(smv[i] - maxv);
    float inv = 1.0f / sum;
    if (tid < S) p[tid] = expf(smv[tid] - maxv) * inv;
    __syncthreads();

    if (tid < 64) {
        int hh = j0 + tid;
        float a0 = 0.f, a1 = 0.f;
#pragma unroll 4
        for (int b = 0; b < 64; b += 2) {
            a0 = fmaf(p[b    ], V0[(size_t)(b    ) * H + hh] + V1[(size_t)(b    ) * H + hh], a0);
            a1 = fmaf(p[b + 1], V0[(size_t)(b + 1) * H + hh] + V1[(size_t)(b + 1) * H + hh], a1);
        }
        a0 = fmaf(p[64], V0[(size_t)64 * H + hh] + V1[(size_t)64 * H + hh], a0);
        att_s[tid] = a0 + a1;
    }
    __syncthreads();

    int jbase = ks * 64;
    float a0 = 0.f, a1 = 0.f, a2 = 0.f, a3 = 0.f;
    for (int j = 0; j < 64; j += 4) {
        a0 = fmaf(att_s[j + 0], lin3[(size_t)(jbase + j + 0) * 1024 + j2], a0);
        a1 = fmaf(att_s[j + 1], lin3[(size_t)(jbase + j + 1) * 1024 + j2], a1);
        a2 = fmaf(att_s[j + 2], lin3[(size_t)(jbase + j + 2) * 1024 + j2], a2);
        a3 = fmaf(att_s[j + 3], lin3[(size_t)(jbase + j + 3) * 1024 + j2], a3);
    }
    tpart[ks * 1024 + j2] = (a0 + a1) + (a2 + a3);
}

// ---------------------------------------------------------------------------
__global__ void lin4_partial_kernel(const float* __restrict__ tpart,
                                    const float* __restrict__ lin4,
                                    float* __restrict__ upart) {
    __shared__ float tl[64];
    int hh = blockIdx.x * 256 + threadIdx.x;
    int ks = blockIdx.y;
    int j2base = ks * 64;

    if (threadIdx.x < 64) {
        int j2 = j2base + threadIdx.x;
        float s = 0.f;
#pragma unroll
        for (int p = 0; p < KS3; ++p) s += tpart[p * 1024 + j2];
        tl[threadIdx.x] = fmaxf(s, 0.f);
    }
    __syncthreads();

    float a0 = 0.f, a1 = 0.f, a2 = 0.f, a3 = 0.f;
    for (int j = 0; j < 64; j += 4) {
        a0 = fmaf(tl[j + 0], lin4[(size_t)(j2base + j + 0) * H + hh], a0);
        a1 = fmaf(tl[j + 1], lin4[(size_t)(j2base + j + 1) * H + hh], a1);
        a2 = fmaf(tl[j + 2], lin4[(size_t)(j2base + j + 2) * H + hh], a2);
        a3 = fmaf(tl[j + 3], lin4[(size_t)(j2base + j + 3) * H + hh], a3);
    }
    upart[ks * H + hh] = (a0 + a1) + (a2 + a3);
}

__global__ void final_out_kernel(const float* __restrict__ upart,
                                 const float* __restrict__ lin5,
                                 float* __restrict__ out) {
    __shared__ float u[H];
    __shared__ float pr[8][64];
    int tid = threadIdx.x;   // 512

    {
        float s = 0.f;
#pragma unroll
        for (int p = 0; p < KS4; ++p) s += upart[p * H + tid];
        u[tid] = tanhf(s);
    }
    __syncthreads();

    int o  = tid & 63;
    int sl = tid >> 6;
    float acc = 0.f;
    int h0 = sl * 64;
#pragma unroll 8
    for (int j = 0; j < 64; ++j) {
        acc = fmaf(u[h0 + j], lin5[(h0 + j) * 64 + o], acc);
    }
    pr[sl][o] = acc;
    __syncthreads();

    if (tid < 64) {
        float s = 0.f;
#pragma unroll
        for (int p = 0; p < 8; ++p) s += pr[p][tid];
        out[tid] = s;
    }
}

// ---------------------------------------------------------------------------
extern "C" void kernel_launch(void* const* d_in, const int* in_sizes, int n_in,
                              void* d_out, int out_size, void* d_ws, size_t ws_size,
                              hipStream_t stream) {
    const float* inputs  = (const float*)d_in[0];
    const float* emb     = (const float*)d_in[1];
    const float* wq      = (const float*)d_in[2];
    const float* wk      = (const float*)d_in[3];
    const float* wv      = (const float*)d_in[4];
    const float* linear1 = (const float*)d_in[5];
    const float* linear2 = (const float*)d_in[6];
    const float* linear3 = (const float*)d_in[7];
    const float* linear4 = (const float*)d_in[8];
    const float* linear5 = (const float*)d_in[9];
    float* out = (float*)d_out;

    float* ws    = (float*)d_ws;
    float* y     = ws;                  // PHS
    float* kqvp  = y     + PHS;         // 9*PHS max (layer1)
    float* att1  = kqvp  + 9 * PHS;     // 3*PHS
    float* att2  = att1  + 3 * PHS;     // PHS
    float* plin1 = att2  + PHS;         // 6*PHS
    float* plin2 = plin1 + 6 * PHS;     // 4*PHS
    float* tpart = plin2 + 4 * PHS;     // 24*1024
    float* upart = tpart + KS3 * 1024;  // 16*512

    const int nb  = HS / 256;           // 130
    const int nbp = PHS / 256;          // 160

    scale_embed_kernel<<<nbp, 256, 0, stream>>>(inputs, emb, y);

    // ---- Layer 1 (KSPLIT=1: 144 blocks, single-partial kqvp) ----
    kqv_gemm_tiled<1><<<dim3(16, 3, 3), 256, 0, stream>>>(wq, wk, wv, 0, y, kqvp);
    attn_kernel<1><<<dim3(S, 3), 256, 0, stream>>>(kqvp, att1);
    mega_lin_kernel<<<234, 256, 0, stream>>>(att1, linear1, linear2, linear3,
                                             plin1, plin2, tpart);
    combine6_relu_kernel<<<nb, 256, 0, stream>>>(plin1, y);

    // ---- Layer 2 (head 2 only; KSPLIT=2: 96 blocks) ----
    kqv_gemm_tiled<2><<<dim3(32, 3, 1), 256, 0, stream>>>(wq, wk, wv, 5, y, kqvp);
    attn_kernel<2><<<dim3(S, 1), 256, 0, stream>>>(kqvp, att2);
    lin2c_combine_kernel<<<nb, 256, 0, stream>>>(att2, linear2, plin2, y);

    // ---- Layer 3 (head 2, row 64) + lin3 tail ----
    kqv_gemm_tiled<2><<<dim3(32, 3, 1), 256, 0, stream>>>(wq, wk, wv, 8, y, kqvp);
    attn3_lin3c_kernel<<<dim3(4, 8), 256, 0, stream>>>(kqvp, linear3, tpart);

    // ---- Final ----
    lin4_partial_kernel<<<dim3(2, KS4), 256, 0, stream>>>(tpart, linear4, upart);
    final_out_kernel<<<1, 512, 0, stream>>>(upart, linear5, out);
}